// Round 1
// baseline (94.070 us; speedup 1.0000x reference)
//
#include <hip/hip_runtime.h>
#include <math.h>

#define EPS 1e-7f

// One block per batch row b. 256 threads = 4 waves.
// Wave w handles t = w, w+4, w+8, ... Each lane holds x[b][t][lane*4 .. lane*4+3].
// Single pass over x: accumulate unnormalized c = sum_t exp(e_t) * x_t and
// denom = sum_t exp(e_t); divide at the end (identical to normalizing first).
__global__ __launch_bounds__(256, 8) void att_output_kernel(
    const float* __restrict__ x,    // [B, T, 256]
    const float* __restrict__ W1,   // [256]
    const float* __restrict__ bias, // [T]
    const float* __restrict__ W2,   // [256, C]
    float* __restrict__ out,        // [B, C]
    int T, int C)
{
    const int b    = blockIdx.x;
    const int tid  = threadIdx.x;
    const int lane = tid & 63;
    const int wave = tid >> 6;

    __shared__ float s_bias[256];   // T <= 256
    __shared__ float s_c[4][256];
    __shared__ float s_den[4];
    __shared__ float s_p[64];
    __shared__ float s_sum;

    if (tid < T) s_bias[tid] = bias[tid];
    __syncthreads();

    // W1 fragment for this lane (same for every t)
    const float4 w1 = *reinterpret_cast<const float4*>(W1 + lane * 4);

    const float* xb = x + (size_t)b * T * 256;

    float4 cacc = make_float4(0.f, 0.f, 0.f, 0.f);
    float  dacc = 0.f;

    for (int t = wave; t < T; t += 4) {
        const float4 xv =
            *reinterpret_cast<const float4*>(xb + (size_t)t * 256 + lane * 4);

        // dot(x[b,t,:], W1) — per-lane partial then 64-lane butterfly reduce
        float d = xv.x * w1.x + xv.y * w1.y + xv.z * w1.z + xv.w * w1.w;
        #pragma unroll
        for (int m = 32; m >= 1; m >>= 1) d += __shfl_xor(d, m, 64);

        const float e   = tanhf(d + s_bias[t]);
        const float wgt = expf(e);          // e in [-1,1] -> no overflow risk

        cacc.x += wgt * xv.x;
        cacc.y += wgt * xv.y;
        cacc.z += wgt * xv.z;
        cacc.w += wgt * xv.w;
        dacc   += wgt;                      // identical across lanes of the wave
    }

    // cross-wave reduction of c (each thread owns column d = tid) and denom
    *reinterpret_cast<float4*>(&s_c[wave][lane * 4]) = cacc;
    if (lane == 0) s_den[wave] = dacc;
    __syncthreads();

    const float den  = s_den[0] + s_den[1] + s_den[2] + s_den[3] + EPS;
    const float cfin =
        (s_c[0][tid] + s_c[1][tid] + s_c[2][tid] + s_c[3][tid]) / den;
    // thread tid is the only reader AND writer of column tid -> no barrier needed
    s_c[0][tid] = cfin;
    __syncthreads();

    // o = exp(c @ W2) / (sum + EPS); C <= 64
    if (tid < C) {
        float dot = 0.f;
        #pragma unroll 4
        for (int d = 0; d < 256; ++d)
            dot += s_c[0][d] * W2[(size_t)d * C + tid];
        s_p[tid] = expf(dot);
    }
    __syncthreads();

    if (tid < 64) {
        float v = (tid < C) ? s_p[tid] : 0.f;
        #pragma unroll
        for (int m = 32; m >= 1; m >>= 1) v += __shfl_xor(v, m, 64);
        if (tid == 0) s_sum = v;
    }
    __syncthreads();

    if (tid < C) out[(size_t)b * C + tid] = s_p[tid] / (s_sum + EPS);
}

extern "C" void kernel_launch(void* const* d_in, const int* in_sizes, int n_in,
                              void* d_out, int out_size, void* d_ws, size_t ws_size,
                              hipStream_t stream) {
    const float* x    = (const float*)d_in[0];
    const float* W1   = (const float*)d_in[1];
    const float* bias = (const float*)d_in[2];
    const float* W2   = (const float*)d_in[3];
    float*       out  = (float*)d_out;

    const int D = in_sizes[1];                 // 256
    const int T = in_sizes[2];                 // 200
    const int C = in_sizes[3] / D;             // 50
    const int B = (int)(in_sizes[0] / ((long long)T * D)); // 2048

    att_output_kernel<<<B, 256, 0, stream>>>(x, W1, bias, W2, out, T, C);
}

// Round 2
// 79.846 us; speedup vs baseline: 1.1781x; 1.1781x over previous
//
#include <hip/hip_runtime.h>
#include <math.h>

#define EPS 1e-7f

__device__ __forceinline__ float fast_exp(float x) {
    return __builtin_amdgcn_exp2f(x * 1.4426950408889634f);   // e^x = 2^(x·log2e)
}
__device__ __forceinline__ float fast_tanh(float x) {
    // tanh(x) = 1 - 2/(e^{2x}+1); rcp is ~1 ulp, inf-safe (rcp(inf)=0)
    float e2 = __builtin_amdgcn_exp2f(x * 2.8853900817779268f); // 2·log2e
    return 1.f - 2.f * __builtin_amdgcn_rcpf(e2 + 1.f);
}

// One block per batch row b. 256 threads = 4 waves.
// Wave w handles row groups t0 = 4w + 16k, 4 rows per iteration.
// Lane l holds x[b][t][l*4 .. l*4+3] (float4, coalesced).
// Grouped reduce: xor1+xor2 per row -> quad sums; lane picks row (l&3);
// xor4..32 finishes all 4 dots at once; tanh/exp once per lane; ordered
// broadcast of the 4 weights via dynamic shfl.
__global__ __launch_bounds__(256, 8) void att_output_kernel(
    const float* __restrict__ x,    // [B, T, 256]
    const float* __restrict__ W1,   // [256]
    const float* __restrict__ bias, // [T]
    const float* __restrict__ W2,   // [256, C]
    float* __restrict__ out,        // [B, C]
    int T, int C)
{
    const int b    = blockIdx.x;
    const int tid  = threadIdx.x;
    const int lane = tid & 63;
    const int wave = tid >> 6;
    const int lj   = lane & 3;

    __shared__ float s_bias[256];     // T <= 256, zero-padded
    __shared__ float s_c[4][256];
    __shared__ float s_den[4];
    __shared__ float s_pp[4][64];
    __shared__ float s_p[64];
    __shared__ float s_sum;

    s_bias[tid] = (tid < T) ? bias[tid] : 0.f;
    __syncthreads();

    const float4 wv = *reinterpret_cast<const float4*>(W1 + lane * 4);
    const float* xb = x + (size_t)b * T * 256;

    float4 cacc = make_float4(0.f, 0.f, 0.f, 0.f);
    float  dacc = 0.f;

    for (int t0 = wave * 4; t0 < T; t0 += 16) {
        const int nv = T - t0;              // valid rows in this group (wave-uniform)
        const float* p0 = xb + (size_t)t0 * 256 + lane * 4;

        float4 xv0 = *reinterpret_cast<const float4*>(p0);
        float4 xv1 = make_float4(0.f,0.f,0.f,0.f);
        float4 xv2 = make_float4(0.f,0.f,0.f,0.f);
        float4 xv3 = make_float4(0.f,0.f,0.f,0.f);
        if (nv > 1) xv1 = *reinterpret_cast<const float4*>(p0 + 256);
        if (nv > 2) xv2 = *reinterpret_cast<const float4*>(p0 + 512);
        if (nv > 3) xv3 = *reinterpret_cast<const float4*>(p0 + 768);

        float q0 = xv0.x*wv.x + xv0.y*wv.y + xv0.z*wv.z + xv0.w*wv.w;
        float q1 = xv1.x*wv.x + xv1.y*wv.y + xv1.z*wv.z + xv1.w*wv.w;
        float q2 = xv2.x*wv.x + xv2.y*wv.y + xv2.z*wv.z + xv2.w*wv.w;
        float q3 = xv3.x*wv.x + xv3.y*wv.y + xv3.z*wv.z + xv3.w*wv.w;

        // quad-level reduce (independent chains)
        q0 += __shfl_xor(q0, 1, 64);  q1 += __shfl_xor(q1, 1, 64);
        q2 += __shfl_xor(q2, 1, 64);  q3 += __shfl_xor(q3, 1, 64);
        q0 += __shfl_xor(q0, 2, 64);  q1 += __shfl_xor(q1, 2, 64);
        q2 += __shfl_xor(q2, 2, 64);  q3 += __shfl_xor(q3, 2, 64);

        // lane l adopts row (l&3)'s quad-sum, then cross-quad reduce
        float sa = (lane & 1) ? q1 : q0;
        float sb = (lane & 1) ? q3 : q2;
        float s  = (lane & 2) ? sb : sa;
        s += __shfl_xor(s, 4, 64);
        s += __shfl_xor(s, 8, 64);
        s += __shfl_xor(s, 16, 64);
        s += __shfl_xor(s, 32, 64);
        // s = full dot(x[b, t0+lj, :], W1)

        const float z = s + s_bias[t0 + lj];
        float w = fast_exp(fast_tanh(z));   // one transcendental pair per lane

        // ordered broadcast: w_m = weight of row t0+m
        const int qbase = lane & ~3;
        float w0 = __shfl(w, qbase + 0, 64);
        float w1 = __shfl(w, qbase + 1, 64);
        float w2 = __shfl(w, qbase + 2, 64);
        float w3 = __shfl(w, qbase + 3, 64);
        if (nv <= 1) w1 = 0.f;
        if (nv <= 2) w2 = 0.f;
        if (nv <= 3) w3 = 0.f;

        cacc.x += w0*xv0.x + w1*xv1.x + w2*xv2.x + w3*xv3.x;
        cacc.y += w0*xv0.y + w1*xv1.y + w2*xv2.y + w3*xv3.y;
        cacc.z += w0*xv0.z + w1*xv1.z + w2*xv2.z + w3*xv3.z;
        cacc.w += w0*xv0.w + w1*xv1.w + w2*xv2.w + w3*xv3.w;
        dacc   += (w0 + w1) + (w2 + w3);    // identical across lanes
    }

    // cross-wave reduction of c (thread tid owns column tid) and denom
    *reinterpret_cast<float4*>(&s_c[wave][lane * 4]) = cacc;
    if (lane == 0) s_den[wave] = dacc;
    __syncthreads();

    const float den  = s_den[0] + s_den[1] + s_den[2] + s_den[3] + EPS;
    const float cfin =
        (s_c[0][tid] + s_c[1][tid] + s_c[2][tid] + s_c[3][tid]) / den;
    s_c[0][tid] = cfin;       // sole reader/writer of column tid
    __syncthreads();

    // o = exp(c @ W2) / (sum + EPS); GEMV split across the 4 waves
    if (lane < C) {
        float dot = 0.f;
        const int d0 = wave * 64;
        #pragma unroll 8
        for (int d = d0; d < d0 + 64; ++d)
            dot += s_c[0][d] * W2[(size_t)d * C + lane];
        s_pp[wave][lane] = dot;
    }
    __syncthreads();

    if (tid < C)
        s_p[tid] = fast_exp(s_pp[0][tid] + s_pp[1][tid] +
                            s_pp[2][tid] + s_pp[3][tid]);
    __syncthreads();

    if (tid < 64) {
        float v = (tid < C) ? s_p[tid] : 0.f;
        #pragma unroll
        for (int m = 32; m >= 1; m >>= 1) v += __shfl_xor(v, m, 64);
        if (tid == 0) s_sum = v;
    }
    __syncthreads();

    if (tid < C) out[(size_t)b * C + tid] = s_p[tid] / (s_sum + EPS);
}

extern "C" void kernel_launch(void* const* d_in, const int* in_sizes, int n_in,
                              void* d_out, int out_size, void* d_ws, size_t ws_size,
                              hipStream_t stream) {
    const float* x    = (const float*)d_in[0];
    const float* W1   = (const float*)d_in[1];
    const float* bias = (const float*)d_in[2];
    const float* W2   = (const float*)d_in[3];
    float*       out  = (float*)d_out;

    const int D = in_sizes[1];                 // 256
    const int T = in_sizes[2];                 // 200
    const int C = in_sizes[3] / D;             // 50
    const int B = (int)(in_sizes[0] / ((long long)T * D)); // 2048

    att_output_kernel<<<B, 256, 0, stream>>>(x, W1, bias, W2, out, T, C);
}

// Round 3
// 79.112 us; speedup vs baseline: 1.1891x; 1.0093x over previous
//
#include <hip/hip_runtime.h>
#include <math.h>

#define EPS 1e-7f

__device__ __forceinline__ float fast_exp(float x) {
    return __builtin_amdgcn_exp2f(x * 1.4426950408889634f);   // e^x = 2^(x·log2e)
}
__device__ __forceinline__ float fast_tanh(float x) {
    // tanh(x) = 1 - 2/(e^{2x}+1); rcp is ~1 ulp, inf-safe
    float e2 = __builtin_amdgcn_exp2f(x * 2.8853900817779268f); // 2·log2e
    return 1.f - 2.f * __builtin_amdgcn_rcpf(e2 + 1.f);
}

// static quad-broadcast: lane <- (lane & ~3) | m   (ds_swizzle BitMode)
#define QB(v, imm) __int_as_float(__builtin_amdgcn_ds_swizzle(__float_as_int(v), imm))

__device__ __forceinline__ void load_group(const float* __restrict__ p, int nv,
                                           float4& a, float4& b,
                                           float4& c, float4& d) {
    a = *reinterpret_cast<const float4*>(p);
    b = (nv > 1) ? *reinterpret_cast<const float4*>(p + 256) : make_float4(0,0,0,0);
    c = (nv > 2) ? *reinterpret_cast<const float4*>(p + 512) : make_float4(0,0,0,0);
    d = (nv > 3) ? *reinterpret_cast<const float4*>(p + 768) : make_float4(0,0,0,0);
}

// One block per batch row b. 256 threads = 4 waves.
// Wave w handles row groups t0 = 4w + 16k, 4 rows per group, depth-1 prefetch:
// next group's loads are in flight while the current group's reduce/tanh/exp
// chain runs, so HBM never idles (anti-convoy).
__global__ __launch_bounds__(256, 8) void att_output_kernel(
    const float* __restrict__ x,    // [B, T, 256]
    const float* __restrict__ W1,   // [256]
    const float* __restrict__ bias, // [T]
    const float* __restrict__ W2,   // [256, C]
    float* __restrict__ out,        // [B, C]
    int T, int C)
{
    const int b    = blockIdx.x;
    const int tid  = threadIdx.x;
    const int lane = tid & 63;
    const int wave = tid >> 6;
    const int lj   = lane & 3;

    __shared__ float s_bias[256];     // T <= 256, zero-padded
    __shared__ float s_c[4][256];
    __shared__ float s_den[4];
    __shared__ float s_pp[4][64];
    __shared__ float s_p[64];
    __shared__ float s_sum;

    s_bias[tid] = (tid < T) ? bias[tid] : 0.f;
    __syncthreads();

    const float4 wv = *reinterpret_cast<const float4*>(W1 + lane * 4);
    const float* base = x + (size_t)b * T * 256 + lane * 4;

    float4 cacc = make_float4(0.f, 0.f, 0.f, 0.f);
    float  dacc = 0.f;

    int t0 = wave * 4;
    float4 xv0, xv1, xv2, xv3;
    if (t0 < T)
        load_group(base + (size_t)t0 * 256, T - t0, xv0, xv1, xv2, xv3);

    for (; t0 < T; t0 += 16) {
        // retire current group into local names; issue next group's loads NOW
        const float4 c0 = xv0, c1 = xv1, c2 = xv2, c3 = xv3;
        const int nv = T - t0;
        const float bi = s_bias[t0 + lj];          // off critical path
        const int tn = t0 + 16;
        if (tn < T)
            load_group(base + (size_t)tn * 256, T - tn, xv0, xv1, xv2, xv3);

        float q0 = c0.x*wv.x + c0.y*wv.y + c0.z*wv.z + c0.w*wv.w;
        float q1 = c1.x*wv.x + c1.y*wv.y + c1.z*wv.z + c1.w*wv.w;
        float q2 = c2.x*wv.x + c2.y*wv.y + c2.z*wv.z + c2.w*wv.w;
        float q3 = c3.x*wv.x + c3.y*wv.y + c3.z*wv.z + c3.w*wv.w;

        // quad-level reduce (independent chains)
        q0 += __shfl_xor(q0, 1, 64);  q1 += __shfl_xor(q1, 1, 64);
        q2 += __shfl_xor(q2, 1, 64);  q3 += __shfl_xor(q3, 1, 64);
        q0 += __shfl_xor(q0, 2, 64);  q1 += __shfl_xor(q1, 2, 64);
        q2 += __shfl_xor(q2, 2, 64);  q3 += __shfl_xor(q3, 2, 64);

        // lane l adopts row (l&3), cross-quad reduce finishes all 4 dots
        float sa = (lane & 1) ? q1 : q0;
        float sb = (lane & 1) ? q3 : q2;
        float s  = (lane & 2) ? sb : sa;
        s += __shfl_xor(s, 4, 64);
        s += __shfl_xor(s, 8, 64);
        s += __shfl_xor(s, 16, 64);
        s += __shfl_xor(s, 32, 64);

        float w = fast_exp(fast_tanh(s + bi));     // one trans pair per lane

        // static quad broadcasts: w_m from lane (lane&~3)|m
        float w0 = QB(w, 0x001C);
        float w1 = QB(w, 0x003C);
        float w2 = QB(w, 0x005C);
        float w3 = QB(w, 0x007C);
        if (nv <= 1) w1 = 0.f;
        if (nv <= 2) w2 = 0.f;
        if (nv <= 3) w3 = 0.f;

        cacc.x += w0*c0.x + w1*c1.x + w2*c2.x + w3*c3.x;
        cacc.y += w0*c0.y + w1*c1.y + w2*c2.y + w3*c3.y;
        cacc.z += w0*c0.z + w1*c1.z + w2*c2.z + w3*c3.z;
        cacc.w += w0*c0.w + w1*c1.w + w2*c2.w + w3*c3.w;
        dacc   += (w0 + w1) + (w2 + w3);           // identical across lanes
    }

    // cross-wave reduction of c (thread tid owns column tid) and denom
    *reinterpret_cast<float4*>(&s_c[wave][lane * 4]) = cacc;
    if (lane == 0) s_den[wave] = dacc;
    __syncthreads();

    const float den  = s_den[0] + s_den[1] + s_den[2] + s_den[3] + EPS;
    const float cfin =
        (s_c[0][tid] + s_c[1][tid] + s_c[2][tid] + s_c[3][tid]) / den;
    s_c[0][tid] = cfin;       // sole reader/writer of column tid
    __syncthreads();

    // o = exp(c @ W2) / (sum + EPS); GEMV split across the 4 waves
    if (lane < C) {
        float dot = 0.f;
        const int d0 = wave * 64;
        #pragma unroll 8
        for (int d = d0; d < d0 + 64; ++d)
            dot += s_c[0][d] * W2[(size_t)d * C + lane];
        s_pp[wave][lane] = dot;
    }
    __syncthreads();

    if (tid < C)
        s_p[tid] = fast_exp(s_pp[0][tid] + s_pp[1][tid] +
                            s_pp[2][tid] + s_pp[3][tid]);
    __syncthreads();

    if (tid < 64) {
        float v = (tid < C) ? s_p[tid] : 0.f;
        #pragma unroll
        for (int m = 32; m >= 1; m >>= 1) v += __shfl_xor(v, m, 64);
        if (tid == 0) s_sum = v;
    }
    __syncthreads();

    if (tid < C) out[(size_t)b * C + tid] = s_p[tid] / (s_sum + EPS);
}

extern "C" void kernel_launch(void* const* d_in, const int* in_sizes, int n_in,
                              void* d_out, int out_size, void* d_ws, size_t ws_size,
                              hipStream_t stream) {
    const float* x    = (const float*)d_in[0];
    const float* W1   = (const float*)d_in[1];
    const float* bias = (const float*)d_in[2];
    const float* W2   = (const float*)d_in[3];
    float*       out  = (float*)d_out;

    const int D = in_sizes[1];                 // 256
    const int T = in_sizes[2];                 // 200
    const int C = in_sizes[3] / D;             // 50
    const int B = (int)(in_sizes[0] / ((long long)T * D)); // 2048

    att_output_kernel<<<B, 256, 0, stream>>>(x, W1, bias, W2, out, T, C);
}

// Round 5
// 68.841 us; speedup vs baseline: 1.3665x; 1.1492x over previous
//
#include <hip/hip_runtime.h>
#include <math.h>

#define EPS 1e-7f

typedef float f32x4 __attribute__((ext_vector_type(4)));   // native vec for nt-load

__device__ __forceinline__ float fast_exp(float x) {
    return __builtin_amdgcn_exp2f(x * 1.4426950408889634f);   // e^x = 2^(x·log2e)
}
__device__ __forceinline__ float fast_tanh(float x) {
    // tanh(x) = 1 - 2/(e^{2x}+1); rcp is ~1 ulp, inf-safe
    float e2 = __builtin_amdgcn_exp2f(x * 2.8853900817779268f); // 2·log2e
    return 1.f - 2.f * __builtin_amdgcn_rcpf(e2 + 1.f);
}

// static quad-broadcast: lane <- (lane & ~3) | m   (ds_swizzle BitMode)
#define QB(v, imm) __int_as_float(__builtin_amdgcn_ds_swizzle(__float_as_int(v), imm))

// non-temporal float4 load: x is pure streaming data, skip cache allocation
__device__ __forceinline__ float4 nt_load4(const float* p) {
    f32x4 v = __builtin_nontemporal_load(reinterpret_cast<const f32x4*>(p));
    return make_float4(v.x, v.y, v.z, v.w);
}

__device__ __forceinline__ void load_group(const float* __restrict__ p, int nv,
                                           float4& a, float4& b,
                                           float4& c, float4& d) {
    a = nt_load4(p);
    b = (nv > 1) ? nt_load4(p + 256) : make_float4(0,0,0,0);
    c = (nv > 2) ? nt_load4(p + 512) : make_float4(0,0,0,0);
    d = (nv > 3) ? nt_load4(p + 768) : make_float4(0,0,0,0);
}

// One block per batch row b. 256 threads = 4 waves.
// Wave w owns the CONTIGUOUS row range [T*w/4, T*(w+1)/4) -> equal work per
// wave. 4 rows per group, depth-1 prefetch. Lane l holds x[b][t][l*4..l*4+3].
__global__ __launch_bounds__(256, 8) void att_output_kernel(
    const float* __restrict__ x,    // [B, T, 256]
    const float* __restrict__ W1,   // [256]
    const float* __restrict__ bias, // [T]
    const float* __restrict__ W2,   // [256, C]
    float* __restrict__ out,        // [B, C]
    int T, int C)
{
    const int b    = blockIdx.x;
    const int tid  = threadIdx.x;
    const int lane = tid & 63;
    const int wave = tid >> 6;
    const int lj   = lane & 3;

    __shared__ float s_bias[260];     // T <= 256, zero-padded (lj overreach safe)
    __shared__ float s_c[4][256];
    __shared__ float s_den[4];
    __shared__ float s_pp[4][64];
    __shared__ float s_p[64];
    __shared__ float s_sum;

    s_bias[tid] = (tid < T) ? bias[tid] : 0.f;
    if (tid < 4) s_bias[256 + tid] = 0.f;
    __syncthreads();

    const float4 wv = *reinterpret_cast<const float4*>(W1 + lane * 4);
    const float* base = x + (size_t)b * T * 256 + lane * 4;

    const int tbeg = (T * wave)     >> 2;   // contiguous per-wave partition
    const int tend = (T * (wave+1)) >> 2;

    float4 cacc = make_float4(0.f, 0.f, 0.f, 0.f);
    float  dacc = 0.f;

    int t0 = tbeg;
    float4 xv0, xv1, xv2, xv3;
    if (t0 < tend)
        load_group(base + (size_t)t0 * 256, tend - t0, xv0, xv1, xv2, xv3);

    for (; t0 < tend; t0 += 4) {
        // retire current group; issue next group's loads immediately
        const float4 c0 = xv0, c1 = xv1, c2 = xv2, c3 = xv3;
        const int nv = tend - t0;                  // wave-uniform
        const float bi = s_bias[t0 + lj];          // off critical path
        const int tn = t0 + 4;
        if (tn < tend)
            load_group(base + (size_t)tn * 256, tend - tn, xv0, xv1, xv2, xv3);

        float q0 = c0.x*wv.x + c0.y*wv.y + c0.z*wv.z + c0.w*wv.w;
        float q1 = c1.x*wv.x + c1.y*wv.y + c1.z*wv.z + c1.w*wv.w;
        float q2 = c2.x*wv.x + c2.y*wv.y + c2.z*wv.z + c2.w*wv.w;
        float q3 = c3.x*wv.x + c3.y*wv.y + c3.z*wv.z + c3.w*wv.w;

        // quad-level reduce (independent chains)
        q0 += __shfl_xor(q0, 1, 64);  q1 += __shfl_xor(q1, 1, 64);
        q2 += __shfl_xor(q2, 1, 64);  q3 += __shfl_xor(q3, 1, 64);
        q0 += __shfl_xor(q0, 2, 64);  q1 += __shfl_xor(q1, 2, 64);
        q2 += __shfl_xor(q2, 2, 64);  q3 += __shfl_xor(q3, 2, 64);

        // lane l adopts row (l&3), cross-quad reduce finishes all 4 dots
        float sa = (lane & 1) ? q1 : q0;
        float sb = (lane & 1) ? q3 : q2;
        float s  = (lane & 2) ? sb : sa;
        s += __shfl_xor(s, 4, 64);
        s += __shfl_xor(s, 8, 64);
        s += __shfl_xor(s, 16, 64);
        s += __shfl_xor(s, 32, 64);

        float w = fast_exp(fast_tanh(s + bi));     // one trans pair per lane

        // static quad broadcasts: w_m from lane (lane&~3)|m
        float w0 = QB(w, 0x001C);
        float w1 = QB(w, 0x003C);
        float w2 = QB(w, 0x005C);
        float w3 = QB(w, 0x007C);
        if (nv <= 1) w1 = 0.f;
        if (nv <= 2) w2 = 0.f;
        if (nv <= 3) w3 = 0.f;

        cacc.x += w0*c0.x + w1*c1.x + w2*c2.x + w3*c3.x;
        cacc.y += w0*c0.y + w1*c1.y + w2*c2.y + w3*c3.y;
        cacc.z += w0*c0.z + w1*c1.z + w2*c2.z + w3*c3.z;
        cacc.w += w0*c0.w + w1*c1.w + w2*c2.w + w3*c3.w;
        dacc   += (w0 + w1) + (w2 + w3);           // identical across lanes
    }

    // cross-wave reduction of c (thread tid owns column tid) and denom
    *reinterpret_cast<float4*>(&s_c[wave][lane * 4]) = cacc;
    if (lane == 0) s_den[wave] = dacc;
    __syncthreads();

    const float den  = s_den[0] + s_den[1] + s_den[2] + s_den[3] + EPS;
    const float cfin =
        (s_c[0][tid] + s_c[1][tid] + s_c[2][tid] + s_c[3][tid]) / den;
    s_c[0][tid] = cfin;       // sole reader/writer of column tid
    __syncthreads();

    // o = exp(c @ W2) / (sum + EPS); GEMV split across the 4 waves
    if (lane < C) {
        float dot = 0.f;
        const int d0 = wave * 64;
        #pragma unroll 8
        for (int d = d0; d < d0 + 64; ++d)
            dot += s_c[0][d] * W2[(size_t)d * C + lane];
        s_pp[wave][lane] = dot;
    }
    __syncthreads();

    if (tid < C)
        s_p[tid] = fast_exp(s_pp[0][tid] + s_pp[1][tid] +
                            s_pp[2][tid] + s_pp[3][tid]);
    __syncthreads();

    if (tid < 64) {
        float v = (tid < C) ? s_p[tid] : 0.f;
        #pragma unroll
        for (int m = 32; m >= 1; m >>= 1) v += __shfl_xor(v, m, 64);
        if (tid == 0) s_sum = v;
    }
    __syncthreads();

    if (tid < C) out[(size_t)b * C + tid] = s_p[tid] / (s_sum + EPS);
}

extern "C" void kernel_launch(void* const* d_in, const int* in_sizes, int n_in,
                              void* d_out, int out_size, void* d_ws, size_t ws_size,
                              hipStream_t stream) {
    const float* x    = (const float*)d_in[0];
    const float* W1   = (const float*)d_in[1];
    const float* bias = (const float*)d_in[2];
    const float* W2   = (const float*)d_in[3];
    float*       out  = (float*)d_out;

    const int D = in_sizes[1];                 // 256
    const int T = in_sizes[2];                 // 200
    const int C = in_sizes[3] / D;             // 50
    const int B = (int)(in_sizes[0] / ((long long)T * D)); // 2048

    att_output_kernel<<<B, 256, 0, stream>>>(x, W1, bias, W2, out, T, C);
}